// Round 4
// baseline (654.015 us; speedup 1.0000x reference)
//
#include <hip/hip_runtime.h>
#include <hip/hip_bf16.h>
#include <stdint.h>

// ---------------- problem constants ----------------
#define NH     16
#define QRANK  1536
#define NOPE_  128
#define QKHD   192
#define B_     2
#define S_     2048
#define MAXSEQ 2048
#define EPS_   1e-6f
#define SCALE_ 0.07216878364870322f  // 192^-0.5

typedef __attribute__((ext_vector_type(4))) float f32x4;
typedef __attribute__((ext_vector_type(8))) short short8;
typedef __attribute__((ext_vector_type(4))) short short4v;

__device__ inline short f2bf(float f){
  uint32_t u = __builtin_bit_cast(uint32_t, f);
  uint32_t r = (u + 0x7FFFu + ((u >> 16) & 1u)) >> 16;
  return (short)(uint16_t)r;
}
__device__ inline float bf2f(short s){
  uint32_t u = ((uint32_t)(uint16_t)s) << 16;
  return __builtin_bit_cast(float, u);
}
// async global->LDS, 16B per lane, LDS dest = wave-uniform base + lane*16
__device__ inline void gload16(const short* g, short* l){
  __builtin_amdgcn_global_load_lds((const __attribute__((address_space(1))) void*)g,
                                   (__attribute__((address_space(3))) void*)l, 16, 0, 0);
}

// ---------------- f32 -> bf16 convert (vectorized) ----------------
__global__ void k_f2b(const float* __restrict__ in, short* __restrict__ out, long n){
  long i = ((long)blockIdx.x * blockDim.x + threadIdx.x) * 4;
  long stride = (long)gridDim.x * blockDim.x * 4;
  for(; i < n; i += stride){
    float4 v = *reinterpret_cast<const float4*>(in + i);
    short4v o;
    o.x = f2bf(v.x); o.y = f2bf(v.y); o.z = f2bf(v.z); o.w = f2bf(v.w);
    *reinterpret_cast<short4v*>(out + i) = o;
  }
}

// ---------------- m97-class GEMM: C[M][N] = A[M][K] @ B[N][K]^T + bias ----------
// 128x128 tile, BK=32, linear LDS, global_load_lds width-16 staging.
// 4 waves 2x2, each wave 64x64 out (4x4 fragments, 16 MFMA / K-step).
template<bool OUT_BF16>
__global__ __launch_bounds__(256)
void k_gemm97(const short* __restrict__ A, const short* __restrict__ Bm,
              const float* __restrict__ bias, float biasScale,
              void* __restrict__ Cp, int M, int N, int K, int ldc)
{
  __shared__ short As[128 * 32];   // 8 KB linear [row][k]
  __shared__ short Bs[128 * 32];   // 8 KB
  const int tid = threadIdx.x;
  const int l = tid & 63, w = tid >> 6;
  const int wr = w >> 1, wc = w & 1;
  const long m0 = (long)blockIdx.x * 128;
  const long n0 = (long)blockIdx.y * 128;
  const int lrow = l & 15, lk8 = (l >> 4) * 8;

  // staging coords: inst j of wave w covers chunks (w*2+j)*64 + l
  int ci0 = (w*2 + 0)*64 + l, ci1 = (w*2 + 1)*64 + l;
  const int r0 = ci0 >> 2, c0 = (ci0 & 3) * 8;
  const int r1 = ci1 >> 2, c1 = (ci1 & 3) * 8;
  const short* a0 = &A[(m0 + r0)*(long)K + c0];
  const short* a1 = &A[(m0 + r1)*(long)K + c1];
  const short* b0 = &Bm[(n0 + r0)*(long)K + c0];
  const short* b1 = &Bm[(n0 + r1)*(long)K + c1];
  short* lA0 = &As[(w*2 + 0)*512];
  short* lA1 = &As[(w*2 + 1)*512];
  short* lB0 = &Bs[(w*2 + 0)*512];
  short* lB1 = &Bs[(w*2 + 1)*512];

  f32x4 acc[4][4];
  #pragma unroll
  for(int m = 0; m < 4; m++)
    #pragma unroll
    for(int n = 0; n < 4; n++) acc[m][n] = (f32x4)0.0f;

  for(int kt = 0; kt < K; kt += 32){
    gload16(a0 + kt, lA0);
    gload16(a1 + kt, lA1);
    gload16(b0 + kt, lB0);
    gload16(b1 + kt, lB1);
    __syncthreads();
    short8 af[4], bfv[4];
    #pragma unroll
    for(int m = 0; m < 4; m++)
      af[m] = *reinterpret_cast<const short8*>(&As[(wr*64 + m*16 + lrow)*32 + lk8]);
    #pragma unroll
    for(int n = 0; n < 4; n++)
      bfv[n] = *reinterpret_cast<const short8*>(&Bs[(wc*64 + n*16 + lrow)*32 + lk8]);
    #pragma unroll
    for(int m = 0; m < 4; m++)
      #pragma unroll
      for(int n = 0; n < 4; n++)
        acc[m][n] = __builtin_amdgcn_mfma_f32_16x16x32_bf16(af[m], bfv[n], acc[m][n], 0, 0, 0);
    __syncthreads();
  }
  #pragma unroll
  for(int m = 0; m < 4; m++){
    int row_l = wr*64 + m*16 + (l >> 4)*4;
    #pragma unroll
    for(int n = 0; n < 4; n++){
      int col = (int)n0 + wc*64 + n*16 + lrow;
      float bv = bias ? bias[col]*biasScale : 0.0f;
      #pragma unroll
      for(int r = 0; r < 4; r++){
        long row = m0 + row_l + r;
        float v = acc[m][n][r] + bv;
        if constexpr (OUT_BF16) ((short*)Cp)[row*(long)ldc + col] = f2bf(v);
        else                    ((float*)Cp)[row*(long)ldc + col] = v;
      }
    }
  }
}

// ---------------- legacy GEMM (for N=192 kva) ----------------
template<int BN, bool OUT_BF16>
__global__ __launch_bounds__(256)
void k_gemm_bt(const short* __restrict__ A, const short* __restrict__ Bm,
               const float* __restrict__ bias, float biasScale,
               void* __restrict__ Cp, int M, int N, int K, int ldc)
{
  constexpr int BM = 128, PAD = 40;
  constexpr int WN = BN / 2, FN = WN / 16;
  __shared__ short As[BM * PAD];
  __shared__ short Bs[BN * PAD];
  const int tid = threadIdx.x;
  const int l = tid & 63, wid = tid >> 6;
  const int wr = wid >> 1, wc = wid & 1;
  const long m0 = (long)blockIdx.x * BM;
  const long n0 = (long)blockIdx.y * BN;
  const int lrow = l & 15, lk = (l >> 4) * 8;

  f32x4 acc[4][FN];
  for(int m = 0; m < 4; m++) for(int n = 0; n < FN; n++) acc[m][n] = (f32x4)0.0f;

  for(int kt = 0; kt < K; kt += 32){
    #pragma unroll
    for(int i = 0; i < BM/64; i++){
      int c = tid + 256*i;
      int row = c >> 2, ko = (c & 3) * 8;
      short8 v = *reinterpret_cast<const short8*>(&A[(m0 + row)*(long)K + kt + ko]);
      *reinterpret_cast<short8*>(&As[row*PAD + ko]) = v;
    }
    #pragma unroll
    for(int i = 0; i < BN/64; i++){
      int c = tid + 256*i;
      int row = c >> 2, ko = (c & 3) * 8;
      short8 v = *reinterpret_cast<const short8*>(&Bm[(n0 + row)*(long)K + kt + ko]);
      *reinterpret_cast<short8*>(&Bs[row*PAD + ko]) = v;
    }
    __syncthreads();
    short8 af[4], bfv[FN];
    #pragma unroll
    for(int m = 0; m < 4; m++)
      af[m] = *reinterpret_cast<const short8*>(&As[(wr*64 + m*16 + lrow)*PAD + lk]);
    #pragma unroll
    for(int n = 0; n < FN; n++)
      bfv[n] = *reinterpret_cast<const short8*>(&Bs[(wc*WN + n*16 + lrow)*PAD + lk]);
    #pragma unroll
    for(int m = 0; m < 4; m++)
      #pragma unroll
      for(int n = 0; n < FN; n++)
        acc[m][n] = __builtin_amdgcn_mfma_f32_16x16x32_bf16(af[m], bfv[n], acc[m][n], 0, 0, 0);
    __syncthreads();
  }
  #pragma unroll
  for(int m = 0; m < 4; m++){
    int row_l = wr*64 + m*16 + (l >> 4)*4;
    #pragma unroll
    for(int n = 0; n < FN; n++){
      int col = (int)n0 + wc*WN + n*16 + (l & 15);
      float bv = bias ? bias[col]*biasScale : 0.0f;
      #pragma unroll
      for(int r = 0; r < 4; r++){
        long row = m0 + row_l + r;
        float v = acc[m][n][r] + bv;
        if constexpr (OUT_BF16) ((short*)Cp)[row*(long)ldc + col] = f2bf(v);
        else                    ((float*)Cp)[row*(long)ldc + col] = v;
      }
    }
  }
}

// ---------------- RMS norm over 1536, rows=4096, bf16 out ----------------
__global__ __launch_bounds__(256)
void k_rms_q(const float* __restrict__ in, const float* __restrict__ w,
             short* __restrict__ out)
{
  const int row = blockIdx.x;
  const int tid = threadIdx.x;
  const float* p = in + (long)row * QRANK;
  float v[6]; float ss = 0.0f;
  #pragma unroll
  for(int i = 0; i < 6; i++){ v[i] = p[tid + 256*i]; ss += v[i]*v[i]; }
  #pragma unroll
  for(int off = 1; off < 64; off <<= 1) ss += __shfl_xor(ss, off);
  __shared__ float red[4];
  if((tid & 63) == 0) red[tid >> 6] = ss;
  __syncthreads();
  ss = red[0] + red[1] + red[2] + red[3];
  float scale = rsqrtf(ss / (float)QRANK + EPS_);
  #pragma unroll
  for(int i = 0; i < 6; i++){
    int c = tid + 256*i;
    out[(long)row*QRANK + c] = f2bf(v[i] * scale * w[c]);
  }
}

// ---------------- q assemble: split nope / rope the pe part ----------------
__global__ __launch_bounds__(256)
void k_qassemble(const short* __restrict__ q, const float* __restrict__ freqs,
                 short* __restrict__ qn, short* __restrict__ qfull)
{
  int wid = threadIdx.x >> 6, l = threadIdx.x & 63;
  long hr = (long)blockIdx.x*4 + wid;      // head-row 0..65535
  long bs = hr >> 4; int h = (int)(hr & 15);
  int s = (int)(bs & (S_ - 1));
  const short* src = q + bs*3072 + h*QKHD;
  qn[hr*128 + l]      = src[l];
  qn[hr*128 + 64 + l] = src[64 + l];
  float v = bf2f(src[128 + l]);
  int i = l >> 1;
  float cs = freqs[(s*32 + i)*2], sn = freqs[(s*32 + i)*2 + 1];
  float pv = __shfl_xor(v, 1);
  float r = (l & 1) ? (pv*sn + v*cs) : (v*cs - pv*sn);
  qfull[hr*QKHD + 128 + l] = f2bf(r);
}

// ---------------- kv: RMS(192) + rope(last 64) + cache merge ----------------
__global__ __launch_bounds__(256)
void k_kvproc(const float* __restrict__ kvf, const float* __restrict__ w,
              const float* __restrict__ freqs, const float* __restrict__ cache,
              const int* __restrict__ sp_ptr, short* __restrict__ kf)
{
  int wid = threadIdx.x >> 6, l = threadIdx.x & 63;
  long row = (long)blockIdx.x*4 + wid;     // 0 .. B*MAXSEQ-1
  int b = (int)(row >> 11);
  int t = (int)(row & (MAXSEQ - 1));
  int sp = sp_ptr[0];
  int end = sp + S_;
  if(t < sp){
    const float* c = cache + row*QKHD;
    kf[row*QKHD + l]       = f2bf(c[l]);
    kf[row*QKHD + 64 + l]  = f2bf(c[64 + l]);
    kf[row*QKHD + 128 + l] = f2bf(c[128 + l]);
    return;
  }
  if(t >= end) return;
  int s = t - sp;
  const float* p = kvf + ((long)b*S_ + s)*QKHD;
  float v0 = p[l], v1 = p[64 + l], v2 = p[128 + l];
  float ss = v0*v0 + v1*v1 + v2*v2;
  #pragma unroll
  for(int off = 1; off < 64; off <<= 1) ss += __shfl_xor(ss, off);
  float scale = rsqrtf(ss / (float)QKHD + EPS_);
  float n0 = v0*scale*w[l], n1 = v1*scale*w[64 + l], n2 = v2*scale*w[128 + l];
  kf[row*QKHD + l]      = f2bf(n0);
  kf[row*QKHD + 64 + l] = f2bf(n1);
  int i = l >> 1;
  float cs = freqs[(s*32 + i)*2], sn = freqs[(s*32 + i)*2 + 1];
  float pv = __shfl_xor(n2, 1);
  float r = (l & 1) ? (pv*sn + n2*cs) : (n2*cs - pv*sn);
  kf[row*QKHD + 128 + l] = f2bf(r);
}

// ---------------- V transpose: KFULL[b][t][0:128] -> VT[b][d][t] ----------------
__global__ __launch_bounds__(256)
void k_vtrans(const short* __restrict__ kf, short* __restrict__ vt)
{
  __shared__ short T[32 * 132];
  const int b = blockIdx.y;
  const int t0 = blockIdx.x * 32;
  const int tid = threadIdx.x;
  #pragma unroll
  for(int i = 0; i < 4; i++){
    int c = tid + 256*i;               // 0..1023
    int tr = c >> 5, dg = c & 31;
    short4v v = *reinterpret_cast<const short4v*>(&kf[((long)b*MAXSEQ + t0 + tr)*QKHD + dg*4]);
    *reinterpret_cast<short4v*>(&T[tr*132 + dg*4]) = v;
  }
  __syncthreads();
  #pragma unroll
  for(int i = 0; i < 4; i++){
    int c = tid + 256*i;               // 0..1023
    int dr = c >> 3, tg = c & 7;
    short4v v;
    v.x = T[(tg*4 + 0)*132 + dr];
    v.y = T[(tg*4 + 1)*132 + dr];
    v.z = T[(tg*4 + 2)*132 + dr];
    v.w = T[(tg*4 + 3)*132 + dr];
    *reinterpret_cast<short4v*>(&vt[((long)b*128 + dr)*MAXSEQ + t0 + tg*4]) = v;
  }
}

// ---------------- flash attention v4 ----------------
// grid (32, 16, 2): one 64-row q-tile per block (longest first), 4 waves.
// 1024 blocks -> 3 blocks/CU resident (LDS 48.5KB), scheduler back-fills.
__global__ __launch_bounds__(256, 3)
void k_attn4(const short* __restrict__ qfull, const short* __restrict__ kf,
             const short* __restrict__ vt, const int* __restrict__ sp_ptr,
             short* __restrict__ oh)
{
  __shared__ short Ks[64 * 192];     // 24.0 KB, swizzled chunks
  __shared__ short Vs[128 * 64];     // 16.0 KB, swizzled chunks
  __shared__ short Ps[4][16 * 68];   //  8.5 KB, pad 4
  const int tid = threadIdx.x;
  const int l = tid & 63, w = tid >> 6;
  const int lrow = l & 15, lhi = l >> 4;
  const int h = blockIdx.y, b = blockIdx.z;
  const int sp = sp_ptr[0];
  const long kbase = (long)b * MAXSEQ;
  const long vbase = (long)b * 128;

  short8 kreg[6], vreg[4];
  const int tile = 31 - (int)blockIdx.x;     // longest first
  const int q0 = tile * 64;

  // hoist Q fragments: wave w owns rows q0+w*16 .. +15, full 192-k
  short8 qa[6];
  {
    int s = q0 + w*16 + lrow;
    const short* qp = qfull + (((long)b*S_ + s)*NH + h)*QKHD + lhi*8;
    #pragma unroll
    for(int ks = 0; ks < 6; ks++) qa[ks] = *reinterpret_cast<const short8*>(qp + ks*32);
  }
  f32x4 o[8];
  #pragma unroll
  for(int df = 0; df < 8; df++) o[df] = (f32x4)0.0f;
  float mrun[4], lrun[4];
  #pragma unroll
  for(int i = 0; i < 4; i++){ mrun[i] = -1e30f; lrun[i] = 0.0f; }

  int hi = q0 + 64 + sp;
  int nt = (hi + 63) >> 6; if(nt > (MAXSEQ >> 6)) nt = MAXSEQ >> 6;

  // ---- prologue: fetch + write tile 0 ----
  {
    #pragma unroll
    for(int i = 0; i < 6; i++){
      int cid = tid + 256*i;  int r = cid/24, c = cid%24;
      kreg[i] = *reinterpret_cast<const short8*>(&kf[(kbase + r)*QKHD + c*8]);
    }
    #pragma unroll
    for(int i = 0; i < 4; i++){
      int cid = tid + 256*i;  int r = cid >> 3, c = cid & 7;
      vreg[i] = *reinterpret_cast<const short8*>(&vt[(vbase + r)*MAXSEQ + c*8]);
    }
    #pragma unroll
    for(int i = 0; i < 6; i++){
      int cid = tid + 256*i;  int r = cid/24, c = cid%24;
      *reinterpret_cast<short8*>(&Ks[r*192 + (c ^ (r & 7))*8]) = kreg[i];
    }
    #pragma unroll
    for(int i = 0; i < 4; i++){
      int cid = tid + 256*i;  int r = cid >> 3, c = cid & 7;
      *reinterpret_cast<short8*>(&Vs[r*64 + (c ^ (r & 7))*8]) = vreg[i];
    }
  }
  __syncthreads();

  for(int t0 = 0; t0 < nt; t0++){
    const int T0 = t0 * 64;
    // ---- issue prefetch of tile t0+1 (lands during compute) ----
    if(t0 + 1 < nt){
      const int Tn = T0 + 64;
      #pragma unroll
      for(int i = 0; i < 6; i++){
        int cid = tid + 256*i;  int r = cid/24, c = cid%24;
        kreg[i] = *reinterpret_cast<const short8*>(&kf[(kbase + Tn + r)*QKHD + c*8]);
      }
      #pragma unroll
      for(int i = 0; i < 4; i++){
        int cid = tid + 256*i;  int r = cid >> 3, c = cid & 7;
        vreg[i] = *reinterpret_cast<const short8*>(&vt[(vbase + r)*MAXSEQ + Tn + c*8]);
      }
    }
    // ---- QK^T: 16q x 64t per wave ----
    f32x4 sc[4];
    #pragma unroll
    for(int tf = 0; tf < 4; tf++) sc[tf] = (f32x4)0.0f;
    #pragma unroll
    for(int ks = 0; ks < 6; ks++){
      #pragma unroll
      for(int tf = 0; tf < 4; tf++){
        int krow = tf*16 + lrow;
        int cs = (ks*4 + lhi) ^ (lrow & 7);
        short8 bfr = *reinterpret_cast<const short8*>(&Ks[krow*192 + cs*8]);
        sc[tf] = __builtin_amdgcn_mfma_f32_16x16x32_bf16(qa[ks], bfr, sc[tf], 0, 0, 0);
      }
    }
    // ---- online softmax ----
    const bool needmask = (T0 + 63 > q0 + w*16 + sp);
    #pragma unroll
    for(int rr = 0; rr < 4; rr++){
      int q = q0 + w*16 + lhi*4 + rr;
      float s0 = sc[0][rr]*SCALE_, s1 = sc[1][rr]*SCALE_;
      float s2 = sc[2][rr]*SCALE_, s3 = sc[3][rr]*SCALE_;
      if(needmask){
        int t = T0 + lrow;
        if(t      > q + sp) s0 = -1e30f;
        if(t + 16 > q + sp) s1 = -1e30f;
        if(t + 32 > q + sp) s2 = -1e30f;
        if(t + 48 > q + sp) s3 = -1e30f;
      }
      float mx = fmaxf(fmaxf(s0, s1), fmaxf(s2, s3));
      #pragma unroll
      for(int off = 1; off < 16; off <<= 1) mx = fmaxf(mx, __shfl_xor(mx, off));
      float mnew = fmaxf(mrun[rr], mx);
      float corr = __expf(mrun[rr] - mnew);
      float p0 = __expf(s0 - mnew), p1 = __expf(s1 - mnew);
      float p2 = __expf(s2 - mnew), p3 = __expf(s3 - mnew);
      float psum = (p0 + p1) + (p2 + p3);
      #pragma unroll
      for(int off = 1; off < 16; off <<= 1) psum += __shfl_xor(psum, off);
      lrun[rr] = lrun[rr]*corr + psum;
      mrun[rr] = mnew;
      #pragma unroll
      for(int df = 0; df < 8; df++) o[df][rr] *= corr;
      int prow = lhi*4 + rr;
      Ps[w][prow*68 + lrow]      = f2bf(p0);
      Ps[w][prow*68 + 16 + lrow] = f2bf(p1);
      Ps[w][prow*68 + 32 + lrow] = f2bf(p2);
      Ps[w][prow*68 + 48 + lrow] = f2bf(p3);
    }
    // ---- PV: O += P @ V  (k=64 in 2 mfma) ----
    short8 pa[2];
    #pragma unroll
    for(int kc = 0; kc < 2; kc++)
      pa[kc] = *reinterpret_cast<const short8*>(&Ps[w][lrow*68 + kc*32 + lhi*8]);
    #pragma unroll
    for(int df = 0; df < 8; df++){
      #pragma unroll
      for(int kc = 0; kc < 2; kc++){
        int vrow = df*16 + lrow;
        int cs = (kc*4 + lhi) ^ (lrow & 7);
        short8 vfr = *reinterpret_cast<const short8*>(&Vs[vrow*64 + cs*8]);
        o[df] = __builtin_amdgcn_mfma_f32_16x16x32_bf16(pa[kc], vfr, o[df], 0, 0, 0);
      }
    }
    __syncthreads();
    // ---- write prefetched tile into LDS ----
    if(t0 + 1 < nt){
      #pragma unroll
      for(int i = 0; i < 6; i++){
        int cid = tid + 256*i;  int r = cid/24, c = cid%24;
        *reinterpret_cast<short8*>(&Ks[r*192 + (c ^ (r & 7))*8]) = kreg[i];
      }
      #pragma unroll
      for(int i = 0; i < 4; i++){
        int cid = tid + 256*i;  int r = cid >> 3, c = cid & 7;
        *reinterpret_cast<short8*>(&Vs[r*64 + (c ^ (r & 7))*8]) = vreg[i];
      }
      __syncthreads();
    }
  }
  // ---- epilogue ----
  #pragma unroll
  for(int rr = 0; rr < 4; rr++){
    int s = q0 + w*16 + lhi*4 + rr;
    float inv = 1.0f / lrun[rr];
    #pragma unroll
    for(int df = 0; df < 8; df++)
      oh[(((long)b*S_ + s)*NH + h)*128 + df*16 + lrow] = f2bf(o[df][rr] * inv);
  }
}

// ---------------- head-sum: (B*S,16,128) -> (B*S,128) ----------------
__global__ void k_redheads(const short* __restrict__ ohp, short* __restrict__ hs){
  long row = blockIdx.x;
  int d = threadIdx.x;
  float acc = 0.0f;
  #pragma unroll
  for(int h = 0; h < NH; h++) acc += bf2f(ohp[(row*NH + h)*128 + d]);
  hs[row*128 + d] = f2bf(acc);
}

// ---------------- ws layout (bytes) ----------------
static constexpr size_t OFF_X16   = 0;
static constexpr size_t OFF_WQA   = 16777216;
static constexpr size_t OFF_WQB   = 23068672;
static constexpr size_t OFF_WKV   = 32505856;
static constexpr size_t OFF_WUK   = 33292288;
static constexpr size_t OFF_WUV   = 33325056;
static constexpr size_t OFF_QNORM = 33849344;
static constexpr size_t OFF_QFULL = 46432256;
static constexpr size_t OFF_KFULL = 71598080;
static constexpr size_t OFF_HSUM  = 73170944;
static constexpr size_t OFF_SCR   = 74219520;   // overlay region 45,088,768 B
static constexpr size_t OFF_QA    = OFF_SCR;              // f32 qa (phase 1)
static constexpr size_t OFF_Q16   = OFF_SCR;              // bf16 q (phase 2)
static constexpr size_t OFF_QN    = OFF_SCR + 25165824;   // bf16 q_nope (phase 2)
static constexpr size_t OFF_KVF   = OFF_SCR + 41943040;   // f32 kv (phase 2)
static constexpr size_t OFF_OH    = OFF_SCR;              // bf16 per-head O (phase 3)
static constexpr size_t OFF_VT    = OFF_SCR + 25165824;   // bf16 V^T (phase 3)

extern "C" void kernel_launch(void* const* d_in, const int* in_sizes, int n_in,
                              void* d_out, int out_size, void* d_ws, size_t ws_size,
                              hipStream_t stream)
{
  const float* x      = (const float*)d_in[0];
  const int*   sp     = (const int*)  d_in[1];
  const float* freqs  = (const float*)d_in[2];
  const float* cache  = (const float*)d_in[4];
  const float* wqa_w  = (const float*)d_in[5];
  const float* wqa_b  = (const float*)d_in[6];
  const float* wqb_w  = (const float*)d_in[7];
  const float* wqb_b  = (const float*)d_in[8];
  const float* qnw    = (const float*)d_in[9];
  const float* wkva_w = (const float*)d_in[10];
  const float* wkva_b = (const float*)d_in[11];
  const float* knw    = (const float*)d_in[12];
  const float* wuk_w  = (const float*)d_in[13];
  const float* wuk_b  = (const float*)d_in[14];
  const float* wuv_w  = (const float*)d_in[15];
  const float* wuv_b  = (const float*)d_in[16];

  char* ws = (char*)d_ws;
  short* X16   = (short*)(ws + OFF_X16);
  short* WQA16 = (short*)(ws + OFF_WQA);
  short* WQB16 = (short*)(ws + OFF_WQB);
  short* WKV16 = (short*)(ws + OFF_WKV);
  short* WUK16 = (short*)(ws + OFF_WUK);
  short* WUV16 = (short*)(ws + OFF_WUV);
  short* QNORM = (short*)(ws + OFF_QNORM);
  short* QFULL = (short*)(ws + OFF_QFULL);
  short* KFULL = (short*)(ws + OFF_KFULL);
  short* HSUM  = (short*)(ws + OFF_HSUM);
  float* QA    = (float*)(ws + OFF_QA);
  short* Q16   = (short*)(ws + OFF_Q16);
  short* QN16  = (short*)(ws + OFF_QN);
  float* KVF   = (float*)(ws + OFF_KVF);
  short* OH16  = (short*)(ws + OFF_OH);
  short* VT16  = (short*)(ws + OFF_VT);

  auto cvt = [&](const float* src, short* dst, long n){
    long blocks = (n/4 + 255) / 256; if(blocks > 2048) blocks = 2048;
    k_f2b<<<(int)blocks, 256, 0, stream>>>(src, dst, n);
  };
  cvt(x,      X16,   (long)B_*S_*2048);
  cvt(wqa_w,  WQA16, (long)QRANK*2048);
  cvt(wqb_w,  WQB16, (long)NH*QKHD*QRANK);
  cvt(wkva_w, WKV16, (long)QKHD*2048);
  cvt(wuk_w,  WUK16, (long)NOPE_*NOPE_);
  cvt(wuv_w,  WUV16, (long)2048*NOPE_);

  // qa = x @ wqa^T + b   (f32)
  k_gemm97<false><<<dim3(32,12), 256, 0, stream>>>(X16, WQA16, wqa_b, 1.0f, QA, 4096, QRANK, 2048, QRANK);
  // rms norm -> bf16
  k_rms_q<<<4096, 256, 0, stream>>>(QA, qnw, QNORM);
  // q = qnorm @ wqb^T + b   (bf16)
  k_gemm97<true><<<dim3(32,24), 256, 0, stream>>>(QNORM, WQB16, wqb_b, 1.0f, Q16, 4096, NH*QKHD, QRANK, NH*QKHD);
  // split nope / rope pe
  k_qassemble<<<16384, 256, 0, stream>>>(Q16, freqs, QN16, QFULL);
  // q_abs = q_nope @ wuk^T + b  -> qfull[...,:128]
  k_gemm97<true><<<dim3(512,1), 256, 0, stream>>>(QN16, WUK16, wuk_b, 1.0f, QFULL, 65536, 128, 128, QKHD);
  // kv = x @ wkva^T + b  (f32)
  k_gemm_bt<64,false><<<dim3(32,3), 256, 0, stream>>>(X16, WKV16, wkva_b, 1.0f, KVF, 4096, QKHD, 2048, QKHD);
  // rms + rope + cache merge -> k_full bf16
  k_kvproc<<<1024, 256, 0, stream>>>(KVF, knw, freqs, cache, sp, KFULL);
  // V transpose -> VT[b][d][t]
  k_vtrans<<<dim3(64,2), 256, 0, stream>>>(KFULL, VT16);
  // flash attention v4 (one q-tile per block, longest first)
  k_attn4<<<dim3(32,16,2), 256, 0, stream>>>(QFULL, KFULL, VT16, sp, OH16);
  // head sum
  k_redheads<<<4096, 128, 0, stream>>>(OH16, HSUM);
  // out = hsum @ wuv^T + 16*b  (f32 -> d_out)
  k_gemm97<false><<<dim3(32,16), 256, 0, stream>>>(HSUM, WUV16, wuv_b, 16.0f, (float*)d_out, 4096, 2048, NOPE_, 2048);
}

// Round 5
// 513.661 us; speedup vs baseline: 1.2732x; 1.2732x over previous
//
#include <hip/hip_runtime.h>
#include <hip/hip_bf16.h>
#include <stdint.h>

// ---------------- problem constants ----------------
#define NH     16
#define QRANK  1536
#define NOPE_  128
#define QKHD   192
#define B_     2
#define S_     2048
#define MAXSEQ 2048
#define EPS_   1e-6f
#define SCALE_ 0.07216878364870322f  // 192^-0.5

typedef __attribute__((ext_vector_type(4))) float f32x4;
typedef __attribute__((ext_vector_type(8))) short short8;
typedef __attribute__((ext_vector_type(4))) short short4v;

__device__ inline short f2bf(float f){
  uint32_t u = __builtin_bit_cast(uint32_t, f);
  uint32_t r = (u + 0x7FFFu + ((u >> 16) & 1u)) >> 16;
  return (short)(uint16_t)r;
}
__device__ inline float bf2f(short s){
  uint32_t u = ((uint32_t)(uint16_t)s) << 16;
  return __builtin_bit_cast(float, u);
}
__device__ inline void gload16(const short* g, short* l){
  __builtin_amdgcn_global_load_lds((const __attribute__((address_space(1))) void*)g,
                                   (__attribute__((address_space(3))) void*)l, 16, 0, 0);
}

// ---------------- f32 -> bf16 convert (vectorized) ----------------
__global__ void k_f2b(const float* __restrict__ in, short* __restrict__ out, long n){
  long i = ((long)blockIdx.x * blockDim.x + threadIdx.x) * 4;
  long stride = (long)gridDim.x * blockDim.x * 4;
  for(; i < n; i += stride){
    float4 v = *reinterpret_cast<const float4*>(in + i);
    short4v o;
    o.x = f2bf(v.x); o.y = f2bf(v.y); o.z = f2bf(v.z); o.w = f2bf(v.w);
    *reinterpret_cast<short4v*>(out + i) = o;
  }
}

// ---------------- m97 GEMM: C[M][N] = A[M][K]@B[N][K]^T + bias ----------------
// BM=128, BN template {64,128}, BK=32, linear LDS, global_load_lds staging.
template<int BN, bool OUT_BF16>
__global__ __launch_bounds__(256)
void k_gemm97(const short* __restrict__ A, const short* __restrict__ Bm,
              const float* __restrict__ bias, float biasScale,
              void* __restrict__ Cp, int M, int N, int K, int ldc)
{
  constexpr int WN = BN / 2, FN = WN / 16;
  __shared__ short As[128 * 32];
  __shared__ short Bs[BN * 32];
  const int tid = threadIdx.x;
  const int l = tid & 63, w = tid >> 6;
  const int wr = w >> 1, wc = w & 1;
  const long m0 = (long)blockIdx.x * 128;
  const long n0 = (long)blockIdx.y * BN;
  const int lrow = l & 15, lk8 = (l >> 4) * 8;

  int ciA0 = (w*2 + 0)*64 + l, ciA1 = (w*2 + 1)*64 + l;
  const short* a0 = &A[(m0 + (ciA0 >> 2))*(long)K + (ciA0 & 3)*8];
  const short* a1 = &A[(m0 + (ciA1 >> 2))*(long)K + (ciA1 & 3)*8];
  short* lA0 = &As[(w*2 + 0)*512];
  short* lA1 = &As[(w*2 + 1)*512];

  const short* b0; const short* b1 = nullptr;
  short* lB0; short* lB1 = nullptr;
  if constexpr (BN == 128){
    int ciB0 = (w*2 + 0)*64 + l, ciB1 = (w*2 + 1)*64 + l;
    b0 = &Bm[(n0 + (ciB0 >> 2))*(long)K + (ciB0 & 3)*8];
    b1 = &Bm[(n0 + (ciB1 >> 2))*(long)K + (ciB1 & 3)*8];
    lB0 = &Bs[(w*2 + 0)*512];
    lB1 = &Bs[(w*2 + 1)*512];
  } else {
    int ciB = w*64 + l;
    b0 = &Bm[(n0 + (ciB >> 2))*(long)K + (ciB & 3)*8];
    lB0 = &Bs[w*512];
  }

  f32x4 acc[4][FN];
  #pragma unroll
  for(int m = 0; m < 4; m++)
    #pragma unroll
    for(int n = 0; n < FN; n++) acc[m][n] = (f32x4)0.0f;

  for(int kt = 0; kt < K; kt += 32){
    gload16(a0 + kt, lA0);
    gload16(a1 + kt, lA1);
    gload16(b0 + kt, lB0);
    if constexpr (BN == 128) gload16(b1 + kt, lB1);
    __syncthreads();
    short8 af[4], bfv[FN];
    #pragma unroll
    for(int m = 0; m < 4; m++)
      af[m] = *reinterpret_cast<const short8*>(&As[(wr*64 + m*16 + lrow)*32 + lk8]);
    #pragma unroll
    for(int n = 0; n < FN; n++)
      bfv[n] = *reinterpret_cast<const short8*>(&Bs[(wc*WN + n*16 + lrow)*32 + lk8]);
    #pragma unroll
    for(int m = 0; m < 4; m++)
      #pragma unroll
      for(int n = 0; n < FN; n++)
        acc[m][n] = __builtin_amdgcn_mfma_f32_16x16x32_bf16(af[m], bfv[n], acc[m][n], 0, 0, 0);
    __syncthreads();
  }
  #pragma unroll
  for(int m = 0; m < 4; m++){
    int row_l = wr*64 + m*16 + (l >> 4)*4;
    #pragma unroll
    for(int n = 0; n < FN; n++){
      int col = (int)n0 + wc*WN + n*16 + lrow;
      float bv = bias ? bias[col]*biasScale : 0.0f;
      #pragma unroll
      for(int r = 0; r < 4; r++){
        long row = m0 + row_l + r;
        float v = acc[m][n][r] + bv;
        if constexpr (OUT_BF16) ((short*)Cp)[row*(long)ldc + col] = f2bf(v);
        else                    ((float*)Cp)[row*(long)ldc + col] = v;
      }
    }
  }
}

// ---------------- legacy GEMM (kva, N=192) ----------------
template<int BN, bool OUT_BF16>
__global__ __launch_bounds__(256)
void k_gemm_bt(const short* __restrict__ A, const short* __restrict__ Bm,
               const float* __restrict__ bias, float biasScale,
               void* __restrict__ Cp, int M, int N, int K, int ldc)
{
  constexpr int BM = 128, PAD = 40;
  constexpr int WN = BN / 2, FN = WN / 16;
  __shared__ short As[BM * PAD];
  __shared__ short Bs[BN * PAD];
  const int tid = threadIdx.x;
  const int l = tid & 63, wid = tid >> 6;
  const int wr = wid >> 1, wc = wid & 1;
  const long m0 = (long)blockIdx.x * BM;
  const long n0 = (long)blockIdx.y * BN;
  const int lrow = l & 15, lk = (l >> 4) * 8;

  f32x4 acc[4][FN];
  for(int m = 0; m < 4; m++) for(int n = 0; n < FN; n++) acc[m][n] = (f32x4)0.0f;

  for(int kt = 0; kt < K; kt += 32){
    #pragma unroll
    for(int i = 0; i < BM/64; i++){
      int c = tid + 256*i;
      int row = c >> 2, ko = (c & 3) * 8;
      short8 v = *reinterpret_cast<const short8*>(&A[(m0 + row)*(long)K + kt + ko]);
      *reinterpret_cast<short8*>(&As[row*PAD + ko]) = v;
    }
    #pragma unroll
    for(int i = 0; i < BN/64; i++){
      int c = tid + 256*i;
      int row = c >> 2, ko = (c & 3) * 8;
      short8 v = *reinterpret_cast<const short8*>(&Bm[(n0 + row)*(long)K + kt + ko]);
      *reinterpret_cast<short8*>(&Bs[row*PAD + ko]) = v;
    }
    __syncthreads();
    short8 af[4], bfv[FN];
    #pragma unroll
    for(int m = 0; m < 4; m++)
      af[m] = *reinterpret_cast<const short8*>(&As[(wr*64 + m*16 + lrow)*PAD + lk]);
    #pragma unroll
    for(int n = 0; n < FN; n++)
      bfv[n] = *reinterpret_cast<const short8*>(&Bs[(wc*WN + n*16 + lrow)*PAD + lk]);
    #pragma unroll
    for(int m = 0; m < 4; m++)
      #pragma unroll
      for(int n = 0; n < FN; n++)
        acc[m][n] = __builtin_amdgcn_mfma_f32_16x16x32_bf16(af[m], bfv[n], acc[m][n], 0, 0, 0);
    __syncthreads();
  }
  #pragma unroll
  for(int m = 0; m < 4; m++){
    int row_l = wr*64 + m*16 + (l >> 4)*4;
    #pragma unroll
    for(int n = 0; n < FN; n++){
      int col = (int)n0 + wc*WN + n*16 + (l & 15);
      float bv = bias ? bias[col]*biasScale : 0.0f;
      #pragma unroll
      for(int r = 0; r < 4; r++){
        long row = m0 + row_l + r;
        float v = acc[m][n][r] + bv;
        if constexpr (OUT_BF16) ((short*)Cp)[row*(long)ldc + col] = f2bf(v);
        else                    ((float*)Cp)[row*(long)ldc + col] = v;
      }
    }
  }
}

// ---------------- RMS norm over 1536, rows=4096, bf16 out ----------------
__global__ __launch_bounds__(256)
void k_rms_q(const float* __restrict__ in, const float* __restrict__ w,
             short* __restrict__ out)
{
  const int row = blockIdx.x;
  const int tid = threadIdx.x;
  const float* p = in + (long)row * QRANK;
  float v[6]; float ss = 0.0f;
  #pragma unroll
  for(int i = 0; i < 6; i++){ v[i] = p[tid + 256*i]; ss += v[i]*v[i]; }
  #pragma unroll
  for(int off = 1; off < 64; off <<= 1) ss += __shfl_xor(ss, off);
  __shared__ float red[4];
  if((tid & 63) == 0) red[tid >> 6] = ss;
  __syncthreads();
  ss = red[0] + red[1] + red[2] + red[3];
  float scale = rsqrtf(ss / (float)QRANK + EPS_);
  #pragma unroll
  for(int i = 0; i < 6; i++){
    int c = tid + 256*i;
    out[(long)row*QRANK + c] = f2bf(v[i] * scale * w[c]);
  }
}

// ---------------- q assemble (vectorized short4): split nope / rope pe ----------
// 48 short4-chunks per head-row: 0..31 nope copy, 32..47 rope.
__global__ __launch_bounds__(256)
void k_qassemble(const short* __restrict__ q, const float* __restrict__ freqs,
                 short* __restrict__ qn, short* __restrict__ qfull)
{
  long idx = (long)blockIdx.x*256 + threadIdx.x;   // < 65536*48
  long hr = idx / 48; int r = (int)(idx % 48);
  long bs = hr >> 4; int h = (int)(hr & 15);
  int s = (int)(bs & (S_ - 1));
  if(r < 32){
    short4v v = *reinterpret_cast<const short4v*>(&q[bs*3072 + h*QKHD + r*4]);
    *reinterpret_cast<short4v*>(&qn[hr*128 + r*4]) = v;
  } else {
    int c = r - 32;   // 0..15
    short4v v = *reinterpret_cast<const short4v*>(&q[bs*3072 + h*QKHD + 128 + c*4]);
    float a0 = bf2f(v.x), b0 = bf2f(v.y), a1 = bf2f(v.z), b1 = bf2f(v.w);
    int p0 = s*32 + c*2, p1 = p0 + 1;
    float cs0 = freqs[p0*2], sn0 = freqs[p0*2 + 1];
    float cs1 = freqs[p1*2], sn1 = freqs[p1*2 + 1];
    short4v o;
    o.x = f2bf(a0*cs0 - b0*sn0); o.y = f2bf(a0*sn0 + b0*cs0);
    o.z = f2bf(a1*cs1 - b1*sn1); o.w = f2bf(a1*sn1 + b1*cs1);
    *reinterpret_cast<short4v*>(&qfull[hr*QKHD + 128 + c*4]) = o;
  }
}

// ---------------- kv: RMS(192) + rope(last 64) + cache merge ----------------
__global__ __launch_bounds__(256)
void k_kvproc(const float* __restrict__ kvf, const float* __restrict__ w,
              const float* __restrict__ freqs, const float* __restrict__ cache,
              const int* __restrict__ sp_ptr, short* __restrict__ kf)
{
  int wid = threadIdx.x >> 6, l = threadIdx.x & 63;
  long row = (long)blockIdx.x*4 + wid;     // 0 .. B*MAXSEQ-1
  int b = (int)(row >> 11);
  int t = (int)(row & (MAXSEQ - 1));
  int sp = sp_ptr[0];
  int end = sp + S_;
  if(t < sp){
    const float* c = cache + row*QKHD;
    kf[row*QKHD + l]       = f2bf(c[l]);
    kf[row*QKHD + 64 + l]  = f2bf(c[64 + l]);
    kf[row*QKHD + 128 + l] = f2bf(c[128 + l]);
    return;
  }
  if(t >= end) return;
  int s = t - sp;
  const float* p = kvf + ((long)b*S_ + s)*QKHD;
  float v0 = p[l], v1 = p[64 + l], v2 = p[128 + l];
  float ss = v0*v0 + v1*v1 + v2*v2;
  #pragma unroll
  for(int off = 1; off < 64; off <<= 1) ss += __shfl_xor(ss, off);
  float scale = rsqrtf(ss / (float)QKHD + EPS_);
  float n0 = v0*scale*w[l], n1 = v1*scale*w[64 + l], n2 = v2*scale*w[128 + l];
  kf[row*QKHD + l]      = f2bf(n0);
  kf[row*QKHD + 64 + l] = f2bf(n1);
  int i = l >> 1;
  float cs = freqs[(s*32 + i)*2], sn = freqs[(s*32 + i)*2 + 1];
  float pv = __shfl_xor(n2, 1);
  float r = (l & 1) ? (pv*sn + n2*cs) : (n2*cs - pv*sn);
  kf[row*QKHD + 128 + l] = f2bf(r);
}

// ---------------- V transpose: KFULL[b][t][0:128] -> VT[b][d][t] ----------------
__global__ __launch_bounds__(256)
void k_vtrans(const short* __restrict__ kf, short* __restrict__ vt)
{
  __shared__ short T[32 * 132];
  const int b = blockIdx.y;
  const int t0 = blockIdx.x * 32;
  const int tid = threadIdx.x;
  #pragma unroll
  for(int i = 0; i < 4; i++){
    int c = tid + 256*i;
    int tr = c >> 5, dg = c & 31;
    short4v v = *reinterpret_cast<const short4v*>(&kf[((long)b*MAXSEQ + t0 + tr)*QKHD + dg*4]);
    *reinterpret_cast<short4v*>(&T[tr*132 + dg*4]) = v;
  }
  __syncthreads();
  #pragma unroll
  for(int i = 0; i < 4; i++){
    int c = tid + 256*i;
    int dr = c >> 3, tg = c & 7;
    short4v v;
    v.x = T[(tg*4 + 0)*132 + dr];
    v.y = T[(tg*4 + 1)*132 + dr];
    v.z = T[(tg*4 + 2)*132 + dr];
    v.w = T[(tg*4 + 3)*132 + dr];
    *reinterpret_cast<short4v*>(&vt[((long)b*128 + dr)*MAXSEQ + t0 + tg*4]) = v;
  }
}

// ---------------- flash attention v5 (paired + defer-max) ----------------
// grid (16,16,2), block 256 = 4 waves x 16 q-rows. Block does tiles (p, 31-p)
// -> exactly 33 kv-iters: perfect balance, all 512 blocks resident.
__global__ __launch_bounds__(256, 3)
void k_attn5(const short* __restrict__ qfull, const short* __restrict__ kf,
             const short* __restrict__ vt, const int* __restrict__ sp_ptr,
             short* __restrict__ oh)
{
  __shared__ short Ks[64 * 192];     // swizzled 16B chunks
  __shared__ short Vs[128 * 64];
  __shared__ short Ps[4][16 * 68];
  const int tid = threadIdx.x;
  const int l = tid & 63, w = tid >> 6;
  const int lrow = l & 15, lhi = l >> 4;
  const int h = blockIdx.y, b = blockIdx.z;
  const int sp = sp_ptr[0];
  const long kbase = (long)b * MAXSEQ;
  const long vbase = (long)b * 128;

  short8 kreg[6], vreg[4];

  #pragma unroll 1
  for(int part = 0; part < 2; part++){
    const int tile = part ? (31 - (int)blockIdx.x) : (int)blockIdx.x;
    const int q0 = tile * 64;

    short8 qa[6];
    {
      int s = q0 + w*16 + lrow;
      const short* qp = qfull + (((long)b*S_ + s)*NH + h)*QKHD + lhi*8;
      #pragma unroll
      for(int ks = 0; ks < 6; ks++) qa[ks] = *reinterpret_cast<const short8*>(qp + ks*32);
    }
    f32x4 o[8];
    #pragma unroll
    for(int df = 0; df < 8; df++) o[df] = (f32x4)0.0f;
    float mrun[4], lrun[4];
    #pragma unroll
    for(int i = 0; i < 4; i++){ mrun[i] = -1e30f; lrun[i] = 0.0f; }

    int hi = q0 + 64 + sp;
    int nt = (hi + 63) >> 6; if(nt > (MAXSEQ >> 6)) nt = MAXSEQ >> 6;

    // prologue: fetch + write tile 0
    {
      #pragma unroll
      for(int i = 0; i < 6; i++){
        int cid = tid + 256*i;  int r = cid/24, c = cid%24;
        kreg[i] = *reinterpret_cast<const short8*>(&kf[(kbase + r)*QKHD + c*8]);
      }
      #pragma unroll
      for(int i = 0; i < 4; i++){
        int cid = tid + 256*i;  int r = cid >> 3, c = cid & 7;
        vreg[i] = *reinterpret_cast<const short8*>(&vt[(vbase + r)*MAXSEQ + c*8]);
      }
      #pragma unroll
      for(int i = 0; i < 6; i++){
        int cid = tid + 256*i;  int r = cid/24, c = cid%24;
        *reinterpret_cast<short8*>(&Ks[r*192 + (c ^ (r & 7))*8]) = kreg[i];
      }
      #pragma unroll
      for(int i = 0; i < 4; i++){
        int cid = tid + 256*i;  int r = cid >> 3, c = cid & 7;
        *reinterpret_cast<short8*>(&Vs[r*64 + (c ^ (r & 7))*8]) = vreg[i];
      }
    }
    __syncthreads();

    for(int t0 = 0; t0 < nt; t0++){
      const int T0 = t0 * 64;
      if(t0 + 1 < nt){
        const int Tn = T0 + 64;
        #pragma unroll
        for(int i = 0; i < 6; i++){
          int cid = tid + 256*i;  int r = cid/24, c = cid%24;
          kreg[i] = *reinterpret_cast<const short8*>(&kf[(kbase + Tn + r)*QKHD + c*8]);
        }
        #pragma unroll
        for(int i = 0; i < 4; i++){
          int cid = tid + 256*i;  int r = cid >> 3, c = cid & 7;
          vreg[i] = *reinterpret_cast<const short8*>(&vt[(vbase + r)*MAXSEQ + Tn + c*8]);
        }
      }
      // QK^T
      f32x4 sc[4];
      #pragma unroll
      for(int tf = 0; tf < 4; tf++) sc[tf] = (f32x4)0.0f;
      #pragma unroll
      for(int ks = 0; ks < 6; ks++){
        #pragma unroll
        for(int tf = 0; tf < 4; tf++){
          int krow = tf*16 + lrow;
          int cs = (ks*4 + lhi) ^ (lrow & 7);
          short8 bfr = *reinterpret_cast<const short8*>(&Ks[krow*192 + cs*8]);
          sc[tf] = __builtin_amdgcn_mfma_f32_16x16x32_bf16(qa[ks], bfr, sc[tf], 0, 0, 0);
        }
      }
      // online softmax with defer-max (T13, THR=8)
      const bool needmask = (T0 + 63 > q0 + w*16 + sp);
      #pragma unroll
      for(int rr = 0; rr < 4; rr++){
        int q = q0 + w*16 + lhi*4 + rr;
        float s0 = sc[0][rr]*SCALE_, s1 = sc[1][rr]*SCALE_;
        float s2 = sc[2][rr]*SCALE_, s3 = sc[3][rr]*SCALE_;
        if(needmask){
          int t = T0 + lrow;
          if(t      > q + sp) s0 = -1e30f;
          if(t + 16 > q + sp) s1 = -1e30f;
          if(t + 32 > q + sp) s2 = -1e30f;
          if(t + 48 > q + sp) s3 = -1e30f;
        }
        float mx = fmaxf(fmaxf(s0, s1), fmaxf(s2, s3));
        #pragma unroll
        for(int off = 1; off < 16; off <<= 1) mx = fmaxf(mx, __shfl_xor(mx, off));
        if(mx > mrun[rr] + 8.0f){
          float corr = __expf(mrun[rr] - mx);
          lrun[rr] *= corr;
          #pragma unroll
          for(int df = 0; df < 8; df++) o[df][rr] *= corr;
          mrun[rr] = mx;
        }
        float p0 = __expf(s0 - mrun[rr]), p1 = __expf(s1 - mrun[rr]);
        float p2 = __expf(s2 - mrun[rr]), p3 = __expf(s3 - mrun[rr]);
        float psum = (p0 + p1) + (p2 + p3);
        #pragma unroll
        for(int off = 1; off < 16; off <<= 1) psum += __shfl_xor(psum, off);
        lrun[rr] += psum;
        int prow = lhi*4 + rr;
        Ps[w][prow*68 + lrow]      = f2bf(p0);
        Ps[w][prow*68 + 16 + lrow] = f2bf(p1);
        Ps[w][prow*68 + 32 + lrow] = f2bf(p2);
        Ps[w][prow*68 + 48 + lrow] = f2bf(p3);
      }
      // PV
      short8 pa[2];
      #pragma unroll
      for(int kc = 0; kc < 2; kc++)
        pa[kc] = *reinterpret_cast<const short8*>(&Ps[w][lrow*68 + kc*32 + lhi*8]);
      #pragma unroll
      for(int df = 0; df < 8; df++){
        #pragma unroll
        for(int kc = 0; kc < 2; kc++){
          int vrow = df*16 + lrow;
          int cs = (kc*4 + lhi) ^ (lrow & 7);
          short8 vfr = *reinterpret_cast<const short8*>(&Vs[vrow*64 + cs*8]);
          o[df] = __builtin_amdgcn_mfma_f32_16x16x32_bf16(pa[kc], vfr, o[df], 0, 0, 0);
        }
      }
      __syncthreads();
      if(t0 + 1 < nt){
        #pragma unroll
        for(int i = 0; i < 6; i++){
          int cid = tid + 256*i;  int r = cid/24, c = cid%24;
          *reinterpret_cast<short8*>(&Ks[r*192 + (c ^ (r & 7))*8]) = kreg[i];
        }
        #pragma unroll
        for(int i = 0; i < 4; i++){
          int cid = tid + 256*i;  int r = cid >> 3, c = cid & 7;
          *reinterpret_cast<short8*>(&Vs[r*64 + (c ^ (r & 7))*8]) = vreg[i];
        }
        __syncthreads();
      }
    }
    // epilogue
    #pragma unroll
    for(int rr = 0; rr < 4; rr++){
      int s = q0 + w*16 + lhi*4 + rr;
      float inv = 1.0f / lrun[rr];
      #pragma unroll
      for(int df = 0; df < 8; df++)
        oh[(((long)b*S_ + s)*NH + h)*128 + df*16 + lrow] = f2bf(o[df][rr] * inv);
    }
  }
}

// ---------------- head-sum (vectorized): (B*S,16,128) -> (B*S,128) ------------
__global__ __launch_bounds__(256)
void k_redheads(const short* __restrict__ ohp, short* __restrict__ hs){
  long idx = (long)blockIdx.x*256 + threadIdx.x;  // < 4096*32
  long row = idx >> 5; int d4 = (int)(idx & 31);
  float a0 = 0, a1 = 0, a2 = 0, a3 = 0;
  #pragma unroll
  for(int h = 0; h < NH; h++){
    short4v v = *reinterpret_cast<const short4v*>(&ohp[(row*NH + h)*128 + d4*4]);
    a0 += bf2f(v.x); a1 += bf2f(v.y); a2 += bf2f(v.z); a3 += bf2f(v.w);
  }
  short4v o; o.x = f2bf(a0); o.y = f2bf(a1); o.z = f2bf(a2); o.w = f2bf(a3);
  *reinterpret_cast<short4v*>(&hs[row*128 + d4*4]) = o;
}

// ---------------- ws layout (bytes) ----------------
static constexpr size_t OFF_X16   = 0;
static constexpr size_t OFF_WQA   = 16777216;
static constexpr size_t OFF_WQB   = 23068672;
static constexpr size_t OFF_WKV   = 32505856;
static constexpr size_t OFF_WUK   = 33292288;
static constexpr size_t OFF_WUV   = 33325056;
static constexpr size_t OFF_QNORM = 33849344;
static constexpr size_t OFF_QFULL = 46432256;
static constexpr size_t OFF_KFULL = 71598080;
static constexpr size_t OFF_HSUM  = 73170944;
static constexpr size_t OFF_SCR   = 74219520;
static constexpr size_t OFF_QA    = OFF_SCR;
static constexpr size_t OFF_Q16   = OFF_SCR;
static constexpr size_t OFF_QN    = OFF_SCR + 25165824;
static constexpr size_t OFF_KVF   = OFF_SCR + 41943040;
static constexpr size_t OFF_OH    = OFF_SCR;
static constexpr size_t OFF_VT    = OFF_SCR + 25165824;

extern "C" void kernel_launch(void* const* d_in, const int* in_sizes, int n_in,
                              void* d_out, int out_size, void* d_ws, size_t ws_size,
                              hipStream_t stream)
{
  const float* x      = (const float*)d_in[0];
  const int*   sp     = (const int*)  d_in[1];
  const float* freqs  = (const float*)d_in[2];
  const float* cache  = (const float*)d_in[4];
  const float* wqa_w  = (const float*)d_in[5];
  const float* wqa_b  = (const float*)d_in[6];
  const float* wqb_w  = (const float*)d_in[7];
  const float* wqb_b  = (const float*)d_in[8];
  const float* qnw    = (const float*)d_in[9];
  const float* wkva_w = (const float*)d_in[10];
  const float* wkva_b = (const float*)d_in[11];
  const float* knw    = (const float*)d_in[12];
  const float* wuk_w  = (const float*)d_in[13];
  const float* wuk_b  = (const float*)d_in[14];
  const float* wuv_w  = (const float*)d_in[15];
  const float* wuv_b  = (const float*)d_in[16];

  char* ws = (char*)d_ws;
  short* X16   = (short*)(ws + OFF_X16);
  short* WQA16 = (short*)(ws + OFF_WQA);
  short* WQB16 = (short*)(ws + OFF_WQB);
  short* WKV16 = (short*)(ws + OFF_WKV);
  short* WUK16 = (short*)(ws + OFF_WUK);
  short* WUV16 = (short*)(ws + OFF_WUV);
  short* QNORM = (short*)(ws + OFF_QNORM);
  short* QFULL = (short*)(ws + OFF_QFULL);
  short* KFULL = (short*)(ws + OFF_KFULL);
  short* HSUM  = (short*)(ws + OFF_HSUM);
  float* QA    = (float*)(ws + OFF_QA);
  short* Q16   = (short*)(ws + OFF_Q16);
  short* QN16  = (short*)(ws + OFF_QN);
  float* KVF   = (float*)(ws + OFF_KVF);
  short* OH16  = (short*)(ws + OFF_OH);
  short* VT16  = (short*)(ws + OFF_VT);

  auto cvt = [&](const float* src, short* dst, long n){
    long blocks = (n/4 + 255) / 256; if(blocks > 2048) blocks = 2048;
    k_f2b<<<(int)blocks, 256, 0, stream>>>(src, dst, n);
  };
  cvt(x,      X16,   (long)B_*S_*2048);
  cvt(wqa_w,  WQA16, (long)QRANK*2048);
  cvt(wqb_w,  WQB16, (long)NH*QKHD*QRANK);
  cvt(wkva_w, WKV16, (long)QKHD*2048);
  cvt(wuk_w,  WUK16, (long)NOPE_*NOPE_);
  cvt(wuv_w,  WUV16, (long)2048*NOPE_);

  // qa = x @ wqa^T + b   (f32), BN=64 -> grid 768
  k_gemm97<64,false><<<dim3(32,24), 256, 0, stream>>>(X16, WQA16, wqa_b, 1.0f, QA, 4096, QRANK, 2048, QRANK);
  // rms norm -> bf16
  k_rms_q<<<4096, 256, 0, stream>>>(QA, qnw, QNORM);
  // q = qnorm @ wqb^T + b   (bf16), BN=128 -> grid 768
  k_gemm97<128,true><<<dim3(32,24), 256, 0, stream>>>(QNORM, WQB16, wqb_b, 1.0f, Q16, 4096, NH*QKHD, QRANK, NH*QKHD);
  // split nope / rope pe (vectorized)
  k_qassemble<<<12288, 256, 0, stream>>>(Q16, freqs, QN16, QFULL);
  // q_abs = q_nope @ wuk^T + b  -> qfull[...,:128]
  k_gemm97<128,true><<<dim3(512,1), 256, 0, stream>>>(QN16, WUK16, wuk_b, 1.0f, QFULL, 65536, 128, 128, QKHD);
  // kv = x @ wkva^T + b  (f32)
  k_gemm_bt<64,false><<<dim3(32,3), 256, 0, stream>>>(X16, WKV16, wkva_b, 1.0f, KVF, 4096, QKHD, 2048, QKHD);
  // rms + rope + cache merge -> k_full bf16
  k_kvproc<<<1024, 256, 0, stream>>>(KVF, knw, freqs, cache, sp, KFULL);
  // V transpose -> VT[b][d][t]
  k_vtrans<<<dim3(64,2), 256, 0, stream>>>(KFULL, VT16);
  // flash attention v5 (paired, defer-max)
  k_attn5<<<dim3(16,16,2), 256, 0, stream>>>(QFULL, KFULL, VT16, sp, OH16);
  // head sum (vectorized)
  k_redheads<<<512, 256, 0, stream>>>(OH16, HSUM);
  // out = hsum @ wuv^T + 16*b  (f32 -> d_out), BN=64 -> grid 1024
  k_gemm97<64,false><<<dim3(32,32), 256, 0, stream>>>(HSUM, WUV16, wuv_b, 16.0f, (float*)d_out, 4096, 2048, NOPE_, 2048);
}